// Round 2
// baseline (64669.592 us; speedup 1.0000x reference)
//
#include <hip/hip_runtime.h>

constexpr int kNB = 2, kNS = 2, kNF = 512, kNPTS = 1024;
constexpr int kNLS = 12, kNLV = 6, kH = 64, kF = 29, kNOUT = 24;
constexpr int kNTGT = kNB * kNF;  // 1024
constexpr float kEPS = 1e-8f;

// LDS float offsets for staged weights (all multiples of 4 floats -> 16B aligned)
constexpr int OW1 = 0;
constexpr int OB1 = OW1 + kF * kH;     // 1856
constexpr int OW2 = OB1 + kH;          // 1920
constexpr int OB2 = OW2 + kH * kH;     // 6016
constexpr int OW3 = OB2 + kH;          // 6080
constexpr int OB3 = OW3 + kH * kH;     // 10176
constexpr int OWO = OB3 + kH;          // 10240
constexpr int OBO = OWO + kH * kNOUT;  // 11776
constexpr int WTOT = OBO + kNOUT;      // 11800 floats = 46.1 KB

__device__ __forceinline__ float wred64(float v) {
#pragma unroll
  for (int off = 32; off > 0; off >>= 1) v += __shfl_xor(v, off, 64);
  return v;
}

__device__ __forceinline__ float silu_f(float t) {
  // t * sigmoid(t); rcp approx is plenty within the 2% threshold
  return t * __builtin_amdgcn_rcpf(1.0f + __expf(-t));
}

// h = silu(x @ W + b). W rows have stride N (row-major KxN), LDS broadcast
// reads via float4. All loops fully unrolled so x/h stay in registers.
template <int K, int N>
__device__ __forceinline__ void dense_silu(const float (&x)[K],
                                           const float* __restrict__ W,
                                           const float* __restrict__ bias,
                                           float (&h)[N]) {
#pragma unroll
  for (int j0 = 0; j0 < N; j0 += 8) {
    float4 a0 = *(const float4*)(bias + j0);
    float4 a1 = *(const float4*)(bias + j0 + 4);
#pragma unroll
    for (int i = 0; i < K; ++i) {
      const float xi = x[i];
      const float4 w0 = *(const float4*)(W + i * N + j0);
      const float4 w1 = *(const float4*)(W + i * N + j0 + 4);
      a0.x = fmaf(xi, w0.x, a0.x);
      a0.y = fmaf(xi, w0.y, a0.y);
      a0.z = fmaf(xi, w0.z, a0.z);
      a0.w = fmaf(xi, w0.w, a0.w);
      a1.x = fmaf(xi, w1.x, a1.x);
      a1.y = fmaf(xi, w1.y, a1.y);
      a1.z = fmaf(xi, w1.z, a1.z);
      a1.w = fmaf(xi, w1.w, a1.w);
    }
    const float av[8] = {a0.x, a0.y, a0.z, a0.w, a1.x, a1.y, a1.z, a1.w};
#pragma unroll
    for (int u = 0; u < 8; ++u) h[j0 + u] = silu_f(av[u]);
  }
}

__device__ __forceinline__ void copy4_f(float* dst, const float* src, int n4,
                                        int tid) {
  const float4* s4 = (const float4*)src;
  float4* d4 = (float4*)dst;
  for (int i = tid; i < n4; i += 512) d4[i] = s4[i];
}

__device__ __forceinline__ void copy_f(float* dst, const float* src, int n,
                                       int tid) {
  for (int i = tid; i < n; i += 512) dst[i] = src[i];
}

__global__ void prep_kernel(const float* __restrict__ normals,
                            float* __restrict__ nrm) {
  const int i = blockIdx.x * blockDim.x + threadIdx.x;
  if (i < kNTGT) {
    const float x = normals[i * 3 + 0];
    const float y = normals[i * 3 + 1];
    const float z = normals[i * 3 + 2];
    const float inv = rsqrtf(x * x + y * y + z * z);
    nrm[i * 3 + 0] = x * inv;
    nrm[i * 3 + 1] = y * inv;
    nrm[i * 3 + 2] = z * inv;
  }
}

// One block per target t; 512 threads = 512 sources. KK=5 for layer 0
// (scal/vecs are all zero -> only logr+legendre features are nonzero),
// KK=29 for layer 1.
template <int KK>
__global__ __launch_bounds__(512, 2) void interact_kernel(
    const float* __restrict__ centroids, const float* __restrict__ nrm,
    const float* __restrict__ areas, const float* __restrict__ refl,
    const float* __restrict__ cW1, const float* __restrict__ cb1,
    const float* __restrict__ cW2, const float* __restrict__ cb2,
    const float* __restrict__ cW3, const float* __restrict__ cb3,
    const float* __restrict__ cWo, const float* __restrict__ cbo, int layer,
    const float* __restrict__ scal_in, const float* __restrict__ vecs_in,
    float* __restrict__ scal_out, float* __restrict__ vecs_out) {
  __shared__ float wbuf[WTOT];
  __shared__ float red[8 * 32];
  const int t = blockIdx.x;
  const int tid = threadIdx.x;
  const float tx = centroids[t * 3 + 0];
  const float ty = centroids[t * 3 + 1];
  const float tz = centroids[t * 3 + 2];

  float accS[kNLS];
  float accV[kNLV * 3];
#pragma unroll
  for (int k = 0; k < kNLS; ++k) accS[k] = 0.f;
#pragma unroll
  for (int k = 0; k < kNLV * 3; ++k) accV[k] = 0.f;

  const int src = tid;  // blockDim.x == kNF

#pragma unroll 1
  for (int bs = 0; bs < kNB * kNS; ++bs) {
    const int b = bs >> 1;
    const int s = bs & 1;
    // ---- stage this combo's weights into LDS ----
    __syncthreads();  // protect previous combo's weights
    const int widx = (layer * kNB + b) * kNS + s;
    copy4_f(wbuf + OW1, cW1 + widx * (kF * kH), (KK * kH) >> 2, tid);
    copy4_f(wbuf + OB1, cb1 + widx * kH, kH >> 2, tid);
    copy4_f(wbuf + OW2, cW2 + widx * (kH * kH), (kH * kH) >> 2, tid);
    copy4_f(wbuf + OB2, cb2 + widx * kH, kH >> 2, tid);
    copy4_f(wbuf + OW3, cW3 + widx * (kH * kH), (kH * kH) >> 2, tid);
    copy4_f(wbuf + OB3, cb3 + widx * kH, kH >> 2, tid);
    copy4_f(wbuf + OWO, cWo + widx * (kH * kNOUT), (kH * kNOUT) >> 2, tid);
    copy4_f(wbuf + OBO, cbo + widx * kNOUT, kNOUT >> 2, tid);
    __syncthreads();

    // ---- geometry + features (recomputed per combo; x dies after L1) ----
    const int sg = b * kNF + src;
    const float px = centroids[sg * 3 + 0];
    const float py = centroids[sg * 3 + 1];
    const float pz = centroids[sg * 3 + 2];
    const float nx = nrm[sg * 3 + 0];
    const float ny = nrm[sg * 3 + 1];
    const float nz = nrm[sg * 3 + 2];
    const float ws_ = areas[sg];
    const float rvx = tx - px, rvy = ty - py, rvz = tz - pz;
    const float r = sqrtf(rvx * rvx + rvy * rvy + rvz * rvz + kEPS * kEPS);
    const float rinv = 1.0f / r;
    const float rhx = rvx * rinv, rhy = rvy * rinv, rhz = rvz * rinv;
    const float c = rhx * nx + rhy * ny + rhz * nz;
    const float c2 = c * c;
    float h1[kH], h2[kH];
    {
      float x[KK];
      x[0] = __logf(r / refl[s]);
      x[1] = 1.0f;
      x[2] = c;
      x[3] = 0.5f * (3.0f * c2 - 1.0f);
      x[4] = 0.5f * c * (5.0f * c2 - 3.0f);
      if constexpr (KK == kF) {
#pragma unroll
        for (int k = 0; k < kNLS; ++k) x[5 + k] = scal_in[sg * kNLS + k];
#pragma unroll
        for (int v = 0; v < kNLV; ++v) {
          const float vx = vecs_in[sg * 18 + v * 3 + 0];
          const float vy = vecs_in[sg * 18 + v * 3 + 1];
          const float vz = vecs_in[sg * 18 + v * 3 + 2];
          x[17 + v] = rhx * vx + rhy * vy + rhz * vz;
          x[23 + v] = nx * vx + ny * vy + nz * vz;
        }
      }
      dense_silu<KK, kH>(x, wbuf + OW1, wbuf + OB1, h1);
    }
    dense_silu<kH, kH>(h1, wbuf + OW2, wbuf + OB2, h2);
    dense_silu<kH, kH>(h2, wbuf + OW3, wbuf + OB3, h1);  // h3 -> h1

    // ---- output layer fused with moment accumulation ----
#pragma unroll
    for (int j0 = 0; j0 < kNOUT; j0 += 8) {
      float4 a0 = *(const float4*)(wbuf + OBO + j0);
      float4 a1 = *(const float4*)(wbuf + OBO + j0 + 4);
#pragma unroll
      for (int i = 0; i < kH; ++i) {
        const float hi = h1[i];
        const float4 w0 = *(const float4*)(wbuf + OWO + i * kNOUT + j0);
        const float4 w1 = *(const float4*)(wbuf + OWO + i * kNOUT + j0 + 4);
        a0.x = fmaf(hi, w0.x, a0.x);
        a0.y = fmaf(hi, w0.y, a0.y);
        a0.z = fmaf(hi, w0.z, a0.z);
        a0.w = fmaf(hi, w0.w, a0.w);
        a1.x = fmaf(hi, w1.x, a1.x);
        a1.y = fmaf(hi, w1.y, a1.y);
        a1.z = fmaf(hi, w1.z, a1.z);
        a1.w = fmaf(hi, w1.w, a1.w);
      }
      const float av[8] = {a0.x, a0.y, a0.z, a0.w, a1.x, a1.y, a1.z, a1.w};
#pragma unroll
      for (int u = 0; u < 8; ++u) {
        const int j = j0 + u;
        const float val = av[u] * ws_;
        if (j < kNLS) {
          accS[j] += val;
        } else if (j < kNLS + kNLV) {
          const int v = j - kNLS;
          accV[v * 3 + 0] += val * rhx;
          accV[v * 3 + 1] += val * rhy;
          accV[v * 3 + 2] += val * rhz;
        } else {
          const int v = j - kNLS - kNLV;
          accV[v * 3 + 0] += val * nx;
          accV[v * 3 + 1] += val * ny;
          accV[v * 3 + 2] += val * nz;
        }
      }
    }
  }

  // ---- block reduction: 30 values over 512 threads ----
#pragma unroll
  for (int k = 0; k < kNLS; ++k) accS[k] = wred64(accS[k]);
#pragma unroll
  for (int k = 0; k < kNLV * 3; ++k) accV[k] = wred64(accV[k]);
  const int wid = tid >> 6, lane = tid & 63;
  __syncthreads();
  if (lane == 0) {
#pragma unroll
    for (int k = 0; k < kNLS; ++k) red[wid * 32 + k] = accS[k];
#pragma unroll
    for (int k = 0; k < kNLV * 3; ++k) red[wid * 32 + kNLS + k] = accV[k];
  }
  __syncthreads();
  if (tid < 30) {
    float sum = 0.f;
#pragma unroll
    for (int w = 0; w < 8; ++w) sum += red[w * 32 + tid];
    if (tid < kNLS)
      scal_out[t * kNLS + tid] = sum;
    else
      vecs_out[t * 18 + (tid - kNLS)] = sum;
  }
}

__global__ __launch_bounds__(512, 2) void final_kernel(
    const float* __restrict__ pred, const float* __restrict__ centroids,
    const float* __restrict__ nrm, const float* __restrict__ areas,
    const float* __restrict__ refl, const float* __restrict__ fW1,
    const float* __restrict__ fb1, const float* __restrict__ fW2,
    const float* __restrict__ fb2, const float* __restrict__ fW3,
    const float* __restrict__ fb3, const float* __restrict__ fWo,
    const float* __restrict__ fbo, const float* __restrict__ scal_in,
    const float* __restrict__ vecs_in, const float* __restrict__ calib,
    float* __restrict__ out) {
  __shared__ float wbuf[WTOT];
  __shared__ float red[8 * 4];
  const int t = blockIdx.x;
  const int tid = threadIdx.x;
  const float tx = pred[t * 3 + 0];
  const float ty = pred[t * 3 + 1];
  const float tz = pred[t * 3 + 2];
  float accP = 0.f, accVx = 0.f, accVy = 0.f, accVz = 0.f;
  const int src = tid;

#pragma unroll 1
  for (int bs = 0; bs < kNB * kNS; ++bs) {
    const int b = bs >> 1;
    const int s = bs & 1;
    __syncthreads();
    const int widx = b * kNS + s;
    copy4_f(wbuf + OW1, fW1 + widx * (kF * kH), (kF * kH) >> 2, tid);
    copy4_f(wbuf + OB1, fb1 + widx * kH, kH >> 2, tid);
    copy4_f(wbuf + OW2, fW2 + widx * (kH * kH), (kH * kH) >> 2, tid);
    copy4_f(wbuf + OB2, fb2 + widx * kH, kH >> 2, tid);
    copy4_f(wbuf + OW3, fW3 + widx * (kH * kH), (kH * kH) >> 2, tid);
    copy4_f(wbuf + OB3, fb3 + widx * kH, kH >> 2, tid);
    copy4_f(wbuf + OWO, fWo + widx * (kH * 3), (kH * 3) >> 2, tid);
    copy_f(wbuf + OBO, fbo + widx * 3, 3, tid);
    __syncthreads();

    const int sg = b * kNF + src;
    const float px = centroids[sg * 3 + 0];
    const float py = centroids[sg * 3 + 1];
    const float pz = centroids[sg * 3 + 2];
    const float nx = nrm[sg * 3 + 0];
    const float ny = nrm[sg * 3 + 1];
    const float nz = nrm[sg * 3 + 2];
    const float ws_ = areas[sg];
    const float rvx = tx - px, rvy = ty - py, rvz = tz - pz;
    const float r = sqrtf(rvx * rvx + rvy * rvy + rvz * rvz + kEPS * kEPS);
    const float rinv = 1.0f / r;
    const float rhx = rvx * rinv, rhy = rvy * rinv, rhz = rvz * rinv;
    const float c = rhx * nx + rhy * ny + rhz * nz;
    const float c2 = c * c;
    float h1[kH], h2[kH];
    {
      float x[kF];
      x[0] = __logf(r / refl[s]);
      x[1] = 1.0f;
      x[2] = c;
      x[3] = 0.5f * (3.0f * c2 - 1.0f);
      x[4] = 0.5f * c * (5.0f * c2 - 3.0f);
#pragma unroll
      for (int k = 0; k < kNLS; ++k) x[5 + k] = scal_in[sg * kNLS + k];
#pragma unroll
      for (int v = 0; v < kNLV; ++v) {
        const float vx = vecs_in[sg * 18 + v * 3 + 0];
        const float vy = vecs_in[sg * 18 + v * 3 + 1];
        const float vz = vecs_in[sg * 18 + v * 3 + 2];
        x[17 + v] = rhx * vx + rhy * vy + rhz * vz;
        x[23 + v] = nx * vx + ny * vy + nz * vz;
      }
      dense_silu<kF, kH>(x, wbuf + OW1, wbuf + OB1, h1);
    }
    dense_silu<kH, kH>(h1, wbuf + OW2, wbuf + OB2, h2);
    dense_silu<kH, kH>(h2, wbuf + OW3, wbuf + OB3, h1);

    float a0 = wbuf[OBO + 0], a1 = wbuf[OBO + 1], a2 = wbuf[OBO + 2];
#pragma unroll
    for (int i = 0; i < kH; ++i) {
      const float hi = h1[i];
      a0 = fmaf(hi, wbuf[OWO + i * 3 + 0], a0);
      a1 = fmaf(hi, wbuf[OWO + i * 3 + 1], a1);
      a2 = fmaf(hi, wbuf[OWO + i * 3 + 2], a2);
    }
    accP += a0 * ws_;
    accVx += ws_ * (a1 * rhx + a2 * nx);
    accVy += ws_ * (a1 * rhy + a2 * ny);
    accVz += ws_ * (a1 * rhz + a2 * nz);
  }

  accP = wred64(accP);
  accVx = wred64(accVx);
  accVy = wred64(accVy);
  accVz = wred64(accVz);
  const int wid = tid >> 6, lane = tid & 63;
  __syncthreads();
  if (lane == 0) {
    red[wid * 4 + 0] = accP;
    red[wid * 4 + 1] = accVx;
    red[wid * 4 + 2] = accVy;
    red[wid * 4 + 3] = accVz;
  }
  __syncthreads();
  if (tid < 4) {
    float sum = 0.f;
#pragma unroll
    for (int w = 0; w < 8; ++w) sum += red[w * 4 + tid];
    const float o = (tid == 0) ? (calib[0] * sum + calib[1]) : (calib[2] * sum);
    out[t * 4 + tid] = o;
  }
}

extern "C" void kernel_launch(void* const* d_in, const int* in_sizes, int n_in,
                              void* d_out, int out_size, void* d_ws,
                              size_t ws_size, hipStream_t stream) {
  const float* pred = (const float*)d_in[0];
  const float* cent = (const float*)d_in[1];
  const float* normals = (const float*)d_in[2];
  const float* areas = (const float*)d_in[3];
  const float* refl = (const float*)d_in[4];
  const float* cW1 = (const float*)d_in[5];
  const float* cb1 = (const float*)d_in[6];
  const float* cW2 = (const float*)d_in[7];
  const float* cb2 = (const float*)d_in[8];
  const float* cW3 = (const float*)d_in[9];
  const float* cb3 = (const float*)d_in[10];
  const float* cWo = (const float*)d_in[11];
  const float* cbo = (const float*)d_in[12];
  const float* fW1 = (const float*)d_in[13];
  const float* fb1 = (const float*)d_in[14];
  const float* fW2 = (const float*)d_in[15];
  const float* fb2 = (const float*)d_in[16];
  const float* fW3 = (const float*)d_in[17];
  const float* fb3 = (const float*)d_in[18];
  const float* fWo = (const float*)d_in[19];
  const float* fbo = (const float*)d_in[20];
  const float* calib = (const float*)d_in[21];

  float* ws = (float*)d_ws;
  float* nrm = ws;                      // 3072
  float* scalA = nrm + kNTGT * 3;       // 12288
  float* vecsA = scalA + kNTGT * kNLS;  // 18432
  float* scalB = vecsA + kNTGT * kNLV * 3;
  float* vecsB = scalB + kNTGT * kNLS;
  float* outp = (float*)d_out;

  prep_kernel<<<(kNTGT + 255) / 256, 256, 0, stream>>>(normals, nrm);
  interact_kernel<5><<<kNTGT, 512, 0, stream>>>(
      cent, nrm, areas, refl, cW1, cb1, cW2, cb2, cW3, cb3, cWo, cbo, 0,
      nullptr, nullptr, scalA, vecsA);
  interact_kernel<kF><<<kNTGT, 512, 0, stream>>>(
      cent, nrm, areas, refl, cW1, cb1, cW2, cb2, cW3, cb3, cWo, cbo, 1, scalA,
      vecsA, scalB, vecsB);
  final_kernel<<<kNPTS, 512, 0, stream>>>(pred, cent, nrm, areas, refl, fW1,
                                          fb1, fW2, fb2, fW3, fb3, fWo, fbo,
                                          scalB, vecsB, calib, outp);
}

// Round 3
// 550.485 us; speedup vs baseline: 117.4775x; 117.4775x over previous
//
#include <hip/hip_runtime.h>

constexpr int kNB = 2, kNS = 2, kNF = 512, kNPTS = 1024;
constexpr int kNLS = 12, kNLV = 6;
constexpr int kNTGT = kNB * kNF;  // 1024

typedef float f32x4 __attribute__((ext_vector_type(4)));
typedef short bf16x8 __attribute__((ext_vector_type(8)));

// Weight-frag layout in ws: per MLP 12288 bf16: W1@0 (4 frags), W2@2048 (8),
// W3@6144 (8), Wo@10240 (4). Frag = 64 lanes x 8 bf16 = 512 elems.
// Frag element p of lane l = W[k][n], k = 32*f + 8*(l>>4) + p, n = 16*ct + (l&15).
// Biases in ws: per MLP 224 f32: b1@0, b2@64, b3@128, bo@192 (padded).
constexpr int kWperMLP = 12288;
constexpr int kBperMLP = 224;

__device__ __forceinline__ unsigned short f2bf(float x) {
  union { float f; unsigned u; } v;
  v.f = x;
  unsigned r = v.u + 0x7fffu + ((v.u >> 16) & 1u);
  return (unsigned short)(r >> 16);
}
__device__ __forceinline__ float bf2f(short b) {
  union { unsigned u; float f; } v;
  v.u = ((unsigned)(unsigned short)b) << 16;
  return v.f;
}
__device__ __forceinline__ unsigned pk2(float a, float b) {
  return (unsigned)f2bf(a) | ((unsigned)f2bf(b) << 16);
}
__device__ __forceinline__ float silu_f(float t) {
  return t * __builtin_amdgcn_rcpf(1.0f + __expf(-t));
}
__device__ __forceinline__ float wred64(float v) {
#pragma unroll
  for (int off = 32; off > 0; off >>= 1) v += __shfl_xor(v, off, 64);
  return v;
}

__global__ void prep_nrm(const float* __restrict__ normals,
                         float* __restrict__ nrm) {
  const int i = blockIdx.x * blockDim.x + threadIdx.x;
  if (i < kNTGT) {
    const float x = normals[i * 3 + 0], y = normals[i * 3 + 1],
                z = normals[i * 3 + 2];
    const float inv = rsqrtf(x * x + y * y + z * z);
    nrm[i * 3 + 0] = x * inv;
    nrm[i * 3 + 1] = y * inv;
    nrm[i * 3 + 2] = z * inv;
  }
}

// Gather weights (KR x NR row-major, fp32) into frag-direct bf16 layout.
template <int KR, int NR, int KP, int NP>
__global__ void prep_w(const float* __restrict__ src, short* __restrict__ dst,
                       int woff, int nmats, int mlp0) {
  constexpr int NCT = NP / 16, NF = KP / 32, NFRAG = NCT * NF;
  const int i = blockIdx.x * blockDim.x + threadIdx.x;
  if (i >= nmats * NFRAG * 64) return;
  const int lane = i & 63;
  const int frag = (i >> 6) % NFRAG;
  const int mat = i / (64 * NFRAG);
  const int ct = frag / NF, f = frag % NF;
  const int k0 = 32 * f + 8 * (lane >> 4);
  const int n = 16 * ct + (lane & 15);
  bf16x8 o;
#pragma unroll
  for (int p = 0; p < 8; ++p) {
    const int k = k0 + p;
    const float v = (k < KR && n < NR) ? src[(mat * KR + k) * NR + n] : 0.f;
    o[p] = (short)f2bf(v);
  }
  *(bf16x8*)(dst + (long)(mlp0 + mat) * kWperMLP + woff + frag * 512 +
             lane * 8) = o;
}

__global__ void prep_b(const float* __restrict__ src, float* __restrict__ dst,
                       int nmats, int NRr, int NPp, int off, int mlp0) {
  const int i = blockIdx.x * blockDim.x + threadIdx.x;
  if (i >= nmats * NPp) return;
  const int mat = i / NPp, j = i % NPp;
  dst[(mlp0 + mat) * kBperMLP + off + j] = (j < NRr) ? src[mat * NRr + j] : 0.f;
}

// Main fused kernel. One block per target; 8 waves x 64; wave owns 64 rows.
// All LDS traffic is wave-private (rows <-> waves aligned) => no barriers
// inside the combo loop.
template <bool FIRST, bool FINAL>
__global__ __launch_bounds__(512, 2) void mlp_main(
    const float* __restrict__ tgt, const float* __restrict__ cent,
    const float* __restrict__ nrm, const float* __restrict__ areas,
    const float* __restrict__ refl, const short* __restrict__ WL,
    const float* __restrict__ BL, int mlp0, const float* __restrict__ scal_in,
    const float* __restrict__ vecs_in, float* __restrict__ scal_out,
    float* __restrict__ vecs_out, const float* __restrict__ calib,
    float* __restrict__ out4) {
  __shared__ short Xb[512 * 32];  // features / out staging, swz ^((m&3)<<4)
  __shared__ short Hb[512 * 64];  // hidden activations, swz ^((m&7)<<4)
  __shared__ float red[8 * 32];
  char* Xc = (char*)Xb;
  char* Hc = (char*)Hb;
  const int tid = threadIdx.x;
  const int lane = tid & 63;
  const int c15 = lane & 15, q = lane >> 4;
  const int wave = tid >> 6;
  const int t = blockIdx.x;
  const float tx = tgt[t * 3 + 0], ty = tgt[t * 3 + 1], tz = tgt[t * 3 + 2];
  const int m = tid;                  // this thread's row (feature/epilogue)
  const int mf = wave * 64 + c15;     // frag-read row base (+ rt*16)

  constexpr int NACC = FINAL ? 4 : 30;
  float acc[NACC];
#pragma unroll
  for (int k = 0; k < NACC; ++k) acc[k] = 0.f;

#pragma unroll 1
  for (int bs = 0; bs < 4; ++bs) {
    const int b = bs >> 1, s = bs & 1;
    const short* wb = WL + (long)(mlp0 + bs) * kWperMLP;
    const float* bb = BL + (mlp0 + bs) * kBperMLP;
    const float rls = refl[s];

    // ---------- features for row m ----------
    const int sg = b * kNF + m;
    const float px = cent[sg * 3 + 0], py = cent[sg * 3 + 1],
                pz = cent[sg * 3 + 2];
    const float nx = nrm[sg * 3 + 0], ny = nrm[sg * 3 + 1],
                nz = nrm[sg * 3 + 2];
    const float wgt = areas[sg];
    const float rvx = tx - px, rvy = ty - py, rvz = tz - pz;
    const float r = sqrtf(rvx * rvx + rvy * rvy + rvz * rvz + 1e-16f);
    const float rinv = 1.f / r;
    const float rhx = rvx * rinv, rhy = rvy * rinv, rhz = rvz * rinv;
    const float cth = rhx * nx + rhy * ny + rhz * nz;
    {
      float f[32];
      f[0] = __logf(r / rls);
      f[1] = 1.f;
      f[2] = cth;
      f[3] = 0.5f * (3.f * cth * cth - 1.f);
      f[4] = 0.5f * cth * (5.f * cth * cth - 3.f);
      if constexpr (!FIRST) {
#pragma unroll
        for (int k = 0; k < kNLS; ++k) f[5 + k] = scal_in[sg * kNLS + k];
#pragma unroll
        for (int v = 0; v < kNLV; ++v) {
          const float vx = vecs_in[sg * 18 + v * 3 + 0];
          const float vy = vecs_in[sg * 18 + v * 3 + 1];
          const float vz = vecs_in[sg * 18 + v * 3 + 2];
          f[17 + v] = rhx * vx + rhy * vy + rhz * vz;
          f[23 + v] = nx * vx + ny * vy + nz * vz;
        }
      } else {
#pragma unroll
        for (int k = 5; k < 29; ++k) f[k] = 0.f;
      }
      f[29] = f[30] = f[31] = 0.f;
#pragma unroll
      for (int g = 0; g < 8; ++g) {
        uint2 u;
        u.x = pk2(f[4 * g + 0], f[4 * g + 1]);
        u.y = pk2(f[4 * g + 2], f[4 * g + 3]);
        *(uint2*)(Xc + ((m * 64 + 8 * g) ^ ((m & 3) << 4))) = u;
      }
    }

    // ---------- layer 1: K=32 (from Xb) ----------
    {
      bf16x8 w1[4];
      f32x4 bv[4];
#pragma unroll
      for (int ct = 0; ct < 4; ++ct) {
        w1[ct] = *(const bf16x8*)(wb + ct * 512 + lane * 8);
        bv[ct] = *(const f32x4*)(bb + 16 * ct + 4 * q);
      }
      f32x4 a[4][4];
#pragma unroll
      for (int rt = 0; rt < 4; ++rt) {
        const int mr = mf + rt * 16;
        const bf16x8 xf =
            *(const bf16x8*)(Xc + ((mr * 64 + 16 * q) ^ ((mr & 3) << 4)));
#pragma unroll
        for (int ct = 0; ct < 4; ++ct)
          a[rt][ct] = __builtin_amdgcn_mfma_f32_16x16x32_bf16(w1[ct], xf,
                                                              bv[ct], 0, 0, 0);
      }
#pragma unroll
      for (int rt = 0; rt < 4; ++rt) {
        const int mr = mf + rt * 16;
#pragma unroll
        for (int ct = 0; ct < 4; ++ct) {
          f32x4 v = a[rt][ct];
          uint2 u;
          u.x = pk2(silu_f(v.x), silu_f(v.y));
          u.y = pk2(silu_f(v.z), silu_f(v.w));
          *(uint2*)(Hc + ((mr * 128 + 32 * ct + 8 * q) ^ ((mr & 7) << 4))) = u;
        }
      }
    }

    // ---------- layers 2,3: K=64, H -> H in place (wave-private) ----------
#pragma unroll 1
    for (int L = 0; L < 2; ++L) {
      const int woff = (L == 0) ? 2048 : 6144;
      const int boff = (L == 0) ? 64 : 128;
      bf16x8 w[4][2];
      f32x4 bv[4];
#pragma unroll
      for (int ct = 0; ct < 4; ++ct) {
        w[ct][0] = *(const bf16x8*)(wb + woff + (ct * 2 + 0) * 512 + lane * 8);
        w[ct][1] = *(const bf16x8*)(wb + woff + (ct * 2 + 1) * 512 + lane * 8);
        bv[ct] = *(const f32x4*)(bb + boff + 16 * ct + 4 * q);
      }
      f32x4 a[4][4];
#pragma unroll
      for (int rt = 0; rt < 4; ++rt) {
        const int mr = mf + rt * 16;
        const bf16x8 h0 =
            *(const bf16x8*)(Hc + ((mr * 128 + 16 * q) ^ ((mr & 7) << 4)));
        const bf16x8 h1 =
            *(const bf16x8*)(Hc + ((mr * 128 + 64 + 16 * q) ^ ((mr & 7) << 4)));
#pragma unroll
        for (int ct = 0; ct < 4; ++ct) {
          f32x4 aa = __builtin_amdgcn_mfma_f32_16x16x32_bf16(w[ct][0], h0,
                                                             bv[ct], 0, 0, 0);
          aa = __builtin_amdgcn_mfma_f32_16x16x32_bf16(w[ct][1], h1, aa, 0, 0,
                                                       0);
          a[rt][ct] = aa;
        }
      }
#pragma unroll
      for (int rt = 0; rt < 4; ++rt) {
        const int mr = mf + rt * 16;
#pragma unroll
        for (int ct = 0; ct < 4; ++ct) {
          f32x4 v = a[rt][ct];
          uint2 u;
          u.x = pk2(silu_f(v.x), silu_f(v.y));
          u.y = pk2(silu_f(v.z), silu_f(v.w));
          *(uint2*)(Hc + ((mr * 128 + 32 * ct + 8 * q) ^ ((mr & 7) << 4))) = u;
        }
      }
    }

    // ---------- output layer (no activation), staged into Xb ----------
    {
      constexpr int NCTO = FINAL ? 1 : 2;
      bf16x8 wo[NCTO][2];
      f32x4 bv[NCTO];
#pragma unroll
      for (int ct = 0; ct < NCTO; ++ct) {
        wo[ct][0] =
            *(const bf16x8*)(wb + 10240 + (ct * 2 + 0) * 512 + lane * 8);
        wo[ct][1] =
            *(const bf16x8*)(wb + 10240 + (ct * 2 + 1) * 512 + lane * 8);
        bv[ct] = *(const f32x4*)(bb + 192 + 16 * ct + 4 * q);
      }
#pragma unroll
      for (int rt = 0; rt < 4; ++rt) {
        const int mr = mf + rt * 16;
        const bf16x8 h0 =
            *(const bf16x8*)(Hc + ((mr * 128 + 16 * q) ^ ((mr & 7) << 4)));
        const bf16x8 h1 =
            *(const bf16x8*)(Hc + ((mr * 128 + 64 + 16 * q) ^ ((mr & 7) << 4)));
#pragma unroll
        for (int ct = 0; ct < NCTO; ++ct) {
          f32x4 aa = __builtin_amdgcn_mfma_f32_16x16x32_bf16(wo[ct][0], h0,
                                                             bv[ct], 0, 0, 0);
          aa = __builtin_amdgcn_mfma_f32_16x16x32_bf16(wo[ct][1], h1, aa, 0, 0,
                                                       0);
          uint2 u;
          u.x = pk2(aa.x, aa.y);
          u.y = pk2(aa.z, aa.w);
          *(uint2*)(Xc + ((mr * 64 + 32 * ct + 8 * q) ^ ((mr & 3) << 4))) = u;
        }
      }
    }

    // ---------- epilogue: thread reads row m's outputs, accumulates ----------
    if constexpr (!FINAL) {
      float o[24];
#pragma unroll
      for (int j = 0; j < 3; ++j) {
        const bf16x8 v =
            *(const bf16x8*)(Xc + ((m * 64 + 16 * j) ^ ((m & 3) << 4)));
#pragma unroll
        for (int i = 0; i < 8; ++i) o[8 * j + i] = bf2f(v[i]);
      }
#pragma unroll
      for (int k = 0; k < kNLS; ++k) acc[k] += o[k] * wgt;
#pragma unroll
      for (int v = 0; v < kNLV; ++v) {
        const float cr = o[12 + v] * wgt, cn = o[18 + v] * wgt;
        acc[12 + v * 3 + 0] += cr * rhx + cn * nx;
        acc[12 + v * 3 + 1] += cr * rhy + cn * ny;
        acc[12 + v * 3 + 2] += cr * rhz + cn * nz;
      }
    } else {
      const bf16x8 v = *(const bf16x8*)(Xc + ((m * 64) ^ ((m & 3) << 4)));
      const float o0 = bf2f(v[0]), o1 = bf2f(v[1]), o2 = bf2f(v[2]);
      acc[0] += o0 * wgt;
      acc[1] += wgt * (o1 * rhx + o2 * nx);
      acc[2] += wgt * (o1 * rhy + o2 * ny);
      acc[3] += wgt * (o1 * rhz + o2 * nz);
    }
  }

  // ---------- block reduction ----------
#pragma unroll
  for (int k = 0; k < NACC; ++k) acc[k] = wred64(acc[k]);
  if (lane == 0) {
#pragma unroll
    for (int k = 0; k < NACC; ++k) red[wave * 32 + k] = acc[k];
  }
  __syncthreads();
  if (tid < NACC) {
    float sum = 0.f;
#pragma unroll
    for (int w = 0; w < 8; ++w) sum += red[w * 32 + tid];
    if constexpr (!FINAL) {
      if (tid < kNLS)
        scal_out[t * kNLS + tid] = sum;
      else
        vecs_out[t * 18 + (tid - kNLS)] = sum;
    } else {
      const float o =
          (tid == 0) ? (calib[0] * sum + calib[1]) : (calib[2] * sum);
      out4[t * 4 + tid] = o;
    }
  }
}

extern "C" void kernel_launch(void* const* d_in, const int* in_sizes, int n_in,
                              void* d_out, int out_size, void* d_ws,
                              size_t ws_size, hipStream_t stream) {
  const float* pred = (const float*)d_in[0];
  const float* cent = (const float*)d_in[1];
  const float* normals = (const float*)d_in[2];
  const float* areas = (const float*)d_in[3];
  const float* refl = (const float*)d_in[4];
  const float* cW1 = (const float*)d_in[5];
  const float* cb1 = (const float*)d_in[6];
  const float* cW2 = (const float*)d_in[7];
  const float* cb2 = (const float*)d_in[8];
  const float* cW3 = (const float*)d_in[9];
  const float* cb3 = (const float*)d_in[10];
  const float* cWo = (const float*)d_in[11];
  const float* cbo = (const float*)d_in[12];
  const float* fW1 = (const float*)d_in[13];
  const float* fb1 = (const float*)d_in[14];
  const float* fW2 = (const float*)d_in[15];
  const float* fb2 = (const float*)d_in[16];
  const float* fW3 = (const float*)d_in[17];
  const float* fb3 = (const float*)d_in[18];
  const float* fWo = (const float*)d_in[19];
  const float* fbo = (const float*)d_in[20];
  const float* calib = (const float*)d_in[21];

  float* ws = (float*)d_ws;
  float* nrmp = ws;                   // 3072
  float* scalA = nrmp + 3072;         // 12288
  float* vecsA = scalA + 12288;       // 18432
  float* scalB = vecsA + 18432;       // 12288
  float* vecsB = scalB + 12288;       // 18432
  float* BLs = vecsB + 18432;         // 12 * 224 = 2688
  short* WLs = (short*)(BLs + 2688);  // 12 * 12288 bf16
  float* outp = (float*)d_out;

  prep_nrm<<<4, 256, 0, stream>>>(normals, nrmp);

  // weights -> frag layout (c-MLPs are mlp 0..7, f-MLPs are 8..11)
  prep_w<29, 64, 32, 64><<<8, 256, 0, stream>>>(cW1, WLs, 0, 8, 0);
  prep_w<64, 64, 64, 64><<<16, 256, 0, stream>>>(cW2, WLs, 2048, 8, 0);
  prep_w<64, 64, 64, 64><<<16, 256, 0, stream>>>(cW3, WLs, 6144, 8, 0);
  prep_w<64, 24, 64, 32><<<8, 256, 0, stream>>>(cWo, WLs, 10240, 8, 0);
  prep_w<29, 64, 32, 64><<<4, 256, 0, stream>>>(fW1, WLs, 0, 4, 8);
  prep_w<64, 64, 64, 64><<<8, 256, 0, stream>>>(fW2, WLs, 2048, 4, 8);
  prep_w<64, 64, 64, 64><<<8, 256, 0, stream>>>(fW3, WLs, 6144, 4, 8);
  prep_w<64, 3, 64, 32><<<4, 256, 0, stream>>>(fWo, WLs, 10240, 4, 8);

  prep_b<<<2, 256, 0, stream>>>(cb1, BLs, 8, 64, 64, 0, 0);
  prep_b<<<2, 256, 0, stream>>>(cb2, BLs, 8, 64, 64, 64, 0);
  prep_b<<<2, 256, 0, stream>>>(cb3, BLs, 8, 64, 64, 128, 0);
  prep_b<<<1, 256, 0, stream>>>(cbo, BLs, 8, 24, 32, 192, 0);
  prep_b<<<1, 256, 0, stream>>>(fb1, BLs, 4, 64, 64, 0, 8);
  prep_b<<<1, 256, 0, stream>>>(fb2, BLs, 4, 64, 64, 64, 8);
  prep_b<<<1, 256, 0, stream>>>(fb3, BLs, 4, 64, 64, 128, 8);
  prep_b<<<1, 256, 0, stream>>>(fbo, BLs, 4, 3, 32, 192, 8);

  mlp_main<true, false><<<kNTGT, 512, 0, stream>>>(
      cent, cent, nrmp, areas, refl, WLs, BLs, 0, nullptr, nullptr, scalA,
      vecsA, nullptr, nullptr);
  mlp_main<false, false><<<kNTGT, 512, 0, stream>>>(
      cent, cent, nrmp, areas, refl, WLs, BLs, 4, scalA, vecsA, scalB, vecsB,
      nullptr, nullptr);
  mlp_main<false, true><<<kNPTS, 512, 0, stream>>>(
      pred, cent, nrmp, areas, refl, WLs, BLs, 8, scalB, vecsB, nullptr,
      nullptr, calib, outp);
}

// Round 7
// 496.227 us; speedup vs baseline: 130.3227x; 1.1093x over previous
//
#include <hip/hip_runtime.h>
#include <hip/hip_bf16.h>

constexpr int kNB = 2, kNS = 2, kNF = 512, kNPTS = 1024;
constexpr int kNLS = 12, kNLV = 6;
constexpr int kNTGT = kNB * kNF;  // 1024

typedef float f32x4 __attribute__((ext_vector_type(4)));
typedef short bf16x8 __attribute__((ext_vector_type(8)));

// Weight-frag layout in ws: per MLP 12288 bf16: W1@0 (4 frags), W2@2048 (8),
// W3@6144 (8), Wo@10240 (4). Frag = 64 lanes x 8 bf16 = 512 elems.
// Frag element p of lane l = W[k][n], k = 32*f + 8*(l>>4) + p, n = 16*ct + (l&15).
// Biases in ws: per MLP 224 f32: b1@0, b2@64, b3@128, bo@192 (padded).
constexpr int kWperMLP = 12288;
constexpr int kBperMLP = 224;

__device__ __forceinline__ unsigned short f2bf(float x) {
  union { float f; unsigned u; } v;
  v.f = x;
  unsigned r = v.u + 0x7fffu + ((v.u >> 16) & 1u);
  return (unsigned short)(r >> 16);
}
__device__ __forceinline__ float bf2f(short b) {
  union { unsigned u; float f; } v;
  v.u = ((unsigned)(unsigned short)b) << 16;
  return v.f;
}
// Native f32->bf16 via the ROCm bf16 API (per-element entry point exists in
// ROCm 7.2; CUDA-style __floats2bfloat162_rn does NOT). Compiler lowers this
// to the HW convert path.  a -> low 16 bits, b -> high 16 bits.
__device__ __forceinline__ unsigned pk2(float a, float b) {
  union { __hip_bfloat162 h2; unsigned u; } cv;
  cv.h2.x = __float2bfloat16(a);
  cv.h2.y = __float2bfloat16(b);
  return cv.u;
}
__device__ __forceinline__ float silu_f(float t) {
  return t * __builtin_amdgcn_rcpf(1.0f + __expf(-t));
}
__device__ __forceinline__ float wred64(float v) {
#pragma unroll
  for (int off = 32; off > 0; off >>= 1) v += __shfl_xor(v, off, 64);
  return v;
}

__global__ void prep_nrm(const float* __restrict__ normals,
                         float* __restrict__ nrm) {
  const int i = blockIdx.x * blockDim.x + threadIdx.x;
  if (i < kNTGT) {
    const float x = normals[i * 3 + 0], y = normals[i * 3 + 1],
                z = normals[i * 3 + 2];
    const float inv = rsqrtf(x * x + y * y + z * z);
    nrm[i * 3 + 0] = x * inv;
    nrm[i * 3 + 1] = y * inv;
    nrm[i * 3 + 2] = z * inv;
  }
}

// Gather weights (KR x NR row-major, fp32) into frag-direct bf16 layout.
template <int KR, int NR, int KP, int NP>
__global__ void prep_w(const float* __restrict__ src, short* __restrict__ dst,
                       int woff, int nmats, int mlp0) {
  constexpr int NCT = NP / 16, NF = KP / 32, NFRAG = NCT * NF;
  const int i = blockIdx.x * blockDim.x + threadIdx.x;
  if (i >= nmats * NFRAG * 64) return;
  const int lane = i & 63;
  const int frag = (i >> 6) % NFRAG;
  const int mat = i / (64 * NFRAG);
  const int ct = frag / NF, f = frag % NF;
  const int k0 = 32 * f + 8 * (lane >> 4);
  const int n = 16 * ct + (lane & 15);
  bf16x8 o;
#pragma unroll
  for (int p = 0; p < 8; ++p) {
    const int k = k0 + p;
    const float v = (k < KR && n < NR) ? src[(mat * KR + k) * NR + n] : 0.f;
    o[p] = (short)f2bf(v);
  }
  *(bf16x8*)(dst + (long)(mlp0 + mat) * kWperMLP + woff + frag * 512 +
             lane * 8) = o;
}

__global__ void prep_b(const float* __restrict__ src, float* __restrict__ dst,
                       int nmats, int NRr, int NPp, int off, int mlp0) {
  const int i = blockIdx.x * blockDim.x + threadIdx.x;
  if (i >= nmats * NPp) return;
  const int mat = i / NPp, j = i % NPp;
  dst[(mlp0 + mat) * kBperMLP + off + j] = (j < NRr) ? src[mat * NRr + j] : 0.f;
}

// Main fused kernel. One block per target; 8 waves x 64; wave owns 64 rows.
// All LDS traffic is wave-private (rows <-> waves aligned) => no barriers
// inside the combo loop.
template <bool FIRST, bool FINAL>
__global__ __launch_bounds__(512, 2) void mlp_main(
    const float* __restrict__ tgt, const float* __restrict__ cent,
    const float* __restrict__ nrm, const float* __restrict__ areas,
    const float* __restrict__ refl, const short* __restrict__ WL,
    const float* __restrict__ BL, int mlp0, const float* __restrict__ scal_in,
    const float* __restrict__ vecs_in, float* __restrict__ scal_out,
    float* __restrict__ vecs_out, const float* __restrict__ calib,
    float* __restrict__ out4) {
  __shared__ short Xb[512 * 32];  // features / out staging, swz ^((m&3)<<4)
  __shared__ short Hb[512 * 64];  // hidden activations, swz ^((m&7)<<4)
  __shared__ float red[8 * 32];
  char* Xc = (char*)Xb;
  char* Hc = (char*)Hb;
  const int tid = threadIdx.x;
  const int lane = tid & 63;
  const int c15 = lane & 15, q = lane >> 4;
  const int wave = tid >> 6;
  const int t = blockIdx.x;
  const float tx = tgt[t * 3 + 0], ty = tgt[t * 3 + 1], tz = tgt[t * 3 + 2];
  const int m = tid;               // this thread's row (feature/epilogue)
  const int mf = wave * 64 + c15;  // frag-read row base (+ rt*16)

  constexpr int NACC = FINAL ? 4 : 30;
  float acc[NACC];
#pragma unroll
  for (int k = 0; k < NACC; ++k) acc[k] = 0.f;

#pragma unroll 1
  for (int bs = 0; bs < 4; ++bs) {
    const int b = bs >> 1, s = bs & 1;
    const short* wb = WL + (long)(mlp0 + bs) * kWperMLP;
    const float* bb = BL + (mlp0 + bs) * kBperMLP;

    // ---------- features for row m ----------
    const int sg = b * kNF + m;
    const float px = cent[sg * 3 + 0], py = cent[sg * 3 + 1],
                pz = cent[sg * 3 + 2];
    const float nx = nrm[sg * 3 + 0], ny = nrm[sg * 3 + 1],
                nz = nrm[sg * 3 + 2];
    const float wgt = areas[sg];
    const float rvx = tx - px, rvy = ty - py, rvz = tz - pz;
    const float r = sqrtf(rvx * rvx + rvy * rvy + rvz * rvz + 1e-16f);
    const float rinv = 1.f / r;
    const float rhx = rvx * rinv, rhy = rvy * rinv, rhz = rvz * rinv;
    const float cth = rhx * nx + rhy * ny + rhz * nz;
    {
      float f[32];
      f[0] = __logf(r / refl[s]);
      f[1] = 1.f;
      f[2] = cth;
      f[3] = 0.5f * (3.f * cth * cth - 1.f);
      f[4] = 0.5f * cth * (5.f * cth * cth - 3.f);
      if constexpr (!FIRST) {
#pragma unroll
        for (int k = 0; k < kNLS; ++k) f[5 + k] = scal_in[sg * kNLS + k];
#pragma unroll
        for (int v = 0; v < kNLV; ++v) {
          const float vx = vecs_in[sg * 18 + v * 3 + 0];
          const float vy = vecs_in[sg * 18 + v * 3 + 1];
          const float vz = vecs_in[sg * 18 + v * 3 + 2];
          f[17 + v] = rhx * vx + rhy * vy + rhz * vz;
          f[23 + v] = nx * vx + ny * vy + nz * vz;
        }
      } else {
#pragma unroll
        for (int k = 5; k < 29; ++k) f[k] = 0.f;
      }
      f[29] = f[30] = f[31] = 0.f;
#pragma unroll
      for (int g = 0; g < 8; ++g) {
        uint2 u;
        u.x = pk2(f[4 * g + 0], f[4 * g + 1]);
        u.y = pk2(f[4 * g + 2], f[4 * g + 3]);
        *(uint2*)(Xc + ((m * 64 + 8 * g) ^ ((m & 3) << 4))) = u;
      }
    }

    // ---------- layer 1: K=32 (from Xb) ----------
    {
      bf16x8 w1[4];
      f32x4 bv[4];
#pragma unroll
      for (int ct = 0; ct < 4; ++ct) {
        w1[ct] = *(const bf16x8*)(wb + ct * 512 + lane * 8);
        bv[ct] = *(const f32x4*)(bb + 16 * ct + 4 * q);
      }
      f32x4 a[4][4];
#pragma unroll
      for (int rt = 0; rt < 4; ++rt) {
        const int mr = mf + rt * 16;
        const bf16x8 xf =
            *(const bf16x8*)(Xc + ((mr * 64 + 16 * q) ^ ((mr & 3) << 4)));
#pragma unroll
        for (int ct = 0; ct < 4; ++ct)
          a[rt][ct] = __builtin_amdgcn_mfma_f32_16x16x32_bf16(w1[ct], xf,
                                                              bv[ct], 0, 0, 0);
      }
#pragma unroll
      for (int rt = 0; rt < 4; ++rt) {
        const int mr = mf + rt * 16;
#pragma unroll
        for (int ct = 0; ct < 4; ++ct) {
          f32x4 v = a[rt][ct];
          uint2 u;
          u.x = pk2(silu_f(v.x), silu_f(v.y));
          u.y = pk2(silu_f(v.z), silu_f(v.w));
          *(uint2*)(Hc + ((mr * 128 + 32 * ct + 8 * q) ^ ((mr & 7) << 4))) = u;
        }
      }
    }

    // ---------- layers 2,3: K=64, H -> H in place (wave-private) ----------
#pragma unroll 1
    for (int L = 0; L < 2; ++L) {
      const int woff = (L == 0) ? 2048 : 6144;
      const int boff = (L == 0) ? 64 : 128;
      bf16x8 w[4][2];
      f32x4 bv[4];
#pragma unroll
      for (int ct = 0; ct < 4; ++ct) {
        w[ct][0] = *(const bf16x8*)(wb + woff + (ct * 2 + 0) * 512 + lane * 8);
        w[ct][1] = *(const bf16x8*)(wb + woff + (ct * 2 + 1) * 512 + lane * 8);
        bv[ct] = *(const f32x4*)(bb + boff + 16 * ct + 4 * q);
      }
      f32x4 a[4][4];
#pragma unroll
      for (int rt = 0; rt < 4; ++rt) {
        const int mr = mf + rt * 16;
        const bf16x8 h0 =
            *(const bf16x8*)(Hc + ((mr * 128 + 16 * q) ^ ((mr & 7) << 4)));
        const bf16x8 h1 =
            *(const bf16x8*)(Hc + ((mr * 128 + 64 + 16 * q) ^ ((mr & 7) << 4)));
#pragma unroll
        for (int ct = 0; ct < 4; ++ct) {
          f32x4 aa = __builtin_amdgcn_mfma_f32_16x16x32_bf16(w[ct][0], h0,
                                                             bv[ct], 0, 0, 0);
          aa = __builtin_amdgcn_mfma_f32_16x16x32_bf16(w[ct][1], h1, aa, 0, 0,
                                                       0);
          a[rt][ct] = aa;
        }
      }
#pragma unroll
      for (int rt = 0; rt < 4; ++rt) {
        const int mr = mf + rt * 16;
#pragma unroll
        for (int ct = 0; ct < 4; ++ct) {
          f32x4 v = a[rt][ct];
          uint2 u;
          u.x = pk2(silu_f(v.x), silu_f(v.y));
          u.y = pk2(silu_f(v.z), silu_f(v.w));
          *(uint2*)(Hc + ((mr * 128 + 32 * ct + 8 * q) ^ ((mr & 7) << 4))) = u;
        }
      }
    }

    // ---------- output layer (no activation), staged into Xb ----------
    {
      constexpr int NCTO = FINAL ? 1 : 2;
      bf16x8 wo[NCTO][2];
      f32x4 bv[NCTO];
#pragma unroll
      for (int ct = 0; ct < NCTO; ++ct) {
        wo[ct][0] =
            *(const bf16x8*)(wb + 10240 + (ct * 2 + 0) * 512 + lane * 8);
        wo[ct][1] =
            *(const bf16x8*)(wb + 10240 + (ct * 2 + 1) * 512 + lane * 8);
        bv[ct] = *(const f32x4*)(bb + 192 + 16 * ct + 4 * q);
      }
#pragma unroll
      for (int rt = 0; rt < 4; ++rt) {
        const int mr = mf + rt * 16;
        const bf16x8 h0 =
            *(const bf16x8*)(Hc + ((mr * 128 + 16 * q) ^ ((mr & 7) << 4)));
        const bf16x8 h1 =
            *(const bf16x8*)(Hc + ((mr * 128 + 64 + 16 * q) ^ ((mr & 7) << 4)));
#pragma unroll
        for (int ct = 0; ct < NCTO; ++ct) {
          f32x4 aa = __builtin_amdgcn_mfma_f32_16x16x32_bf16(wo[ct][0], h0,
                                                             bv[ct], 0, 0, 0);
          aa = __builtin_amdgcn_mfma_f32_16x16x32_bf16(wo[ct][1], h1, aa, 0, 0,
                                                       0);
          uint2 u;
          u.x = pk2(aa.x, aa.y);
          u.y = pk2(aa.z, aa.w);
          *(uint2*)(Xc + ((mr * 64 + 32 * ct + 8 * q) ^ ((mr & 3) << 4))) = u;
        }
      }
    }

    // ---------- epilogue: thread reads row m's outputs, accumulates ----------
    if constexpr (!FINAL) {
      float o[24];
#pragma unroll
      for (int j = 0; j < 3; ++j) {
        const bf16x8 v =
            *(const bf16x8*)(Xc + ((m * 64 + 16 * j) ^ ((m & 3) << 4)));
#pragma unroll
        for (int i = 0; i < 8; ++i) o[8 * j + i] = bf2f(v[i]);
      }
#pragma unroll
      for (int k = 0; k < kNLS; ++k) acc[k] += o[k] * wgt;
#pragma unroll
      for (int v = 0; v < kNLV; ++v) {
        const float cr = o[12 + v] * wgt, cn = o[18 + v] * wgt;
        acc[12 + v * 3 + 0] += cr * rhx + cn * nx;
        acc[12 + v * 3 + 1] += cr * rhy + cn * ny;
        acc[12 + v * 3 + 2] += cr * rhz + cn * nz;
      }
    } else {
      const bf16x8 v = *(const bf16x8*)(Xc + ((m * 64) ^ ((m & 3) << 4)));
      const float o0 = bf2f(v[0]), o1 = bf2f(v[1]), o2 = bf2f(v[2]);
      acc[0] += o0 * wgt;
      acc[1] += wgt * (o1 * rhx + o2 * nx);
      acc[2] += wgt * (o1 * rhy + o2 * ny);
      acc[3] += wgt * (o1 * rhz + o2 * nz);
    }
  }

  // ---------- block reduction ----------
#pragma unroll
  for (int k = 0; k < NACC; ++k) acc[k] = wred64(acc[k]);
  if (lane == 0) {
#pragma unroll
    for (int k = 0; k < NACC; ++k) red[wave * 32 + k] = acc[k];
  }
  __syncthreads();
  if (tid < NACC) {
    float sum = 0.f;
#pragma unroll
    for (int w = 0; w < 8; ++w) sum += red[w * 32 + tid];
    if constexpr (!FINAL) {
      if (tid < kNLS)
        scal_out[t * kNLS + tid] = sum;
      else
        vecs_out[t * 18 + (tid - kNLS)] = sum;
    } else {
      const float o =
          (tid == 0) ? (calib[0] * sum + calib[1]) : (calib[2] * sum);
      out4[t * 4 + tid] = o;
    }
  }
}

extern "C" void kernel_launch(void* const* d_in, const int* in_sizes, int n_in,
                              void* d_out, int out_size, void* d_ws,
                              size_t ws_size, hipStream_t stream) {
  const float* pred = (const float*)d_in[0];
  const float* cent = (const float*)d_in[1];
  const float* normals = (const float*)d_in[2];
  const float* areas = (const float*)d_in[3];
  const float* refl = (const float*)d_in[4];
  const float* cW1 = (const float*)d_in[5];
  const float* cb1 = (const float*)d_in[6];
  const float* cW2 = (const float*)d_in[7];
  const float* cb2 = (const float*)d_in[8];
  const float* cW3 = (const float*)d_in[9];
  const float* cb3 = (const float*)d_in[10];
  const float* cWo = (const float*)d_in[11];
  const float* cbo = (const float*)d_in[12];
  const float* fW1 = (const float*)d_in[13];
  const float* fb1 = (const float*)d_in[14];
  const float* fW2 = (const float*)d_in[15];
  const float* fb2 = (const float*)d_in[16];
  const float* fW3 = (const float*)d_in[17];
  const float* fb3 = (const float*)d_in[18];
  const float* fWo = (const float*)d_in[19];
  const float* fbo = (const float*)d_in[20];
  const float* calib = (const float*)d_in[21];

  float* ws = (float*)d_ws;
  float* nrmp = ws;                   // 3072
  float* scalA = nrmp + 3072;         // 12288
  float* vecsA = scalA + 12288;       // 18432
  float* scalB = vecsA + 18432;       // 12288
  float* vecsB = scalB + 12288;       // 18432
  float* BLs = vecsB + 18432;         // 12 * 224 = 2688
  short* WLs = (short*)(BLs + 2688);  // 12 * 12288 bf16
  float* outp = (float*)d_out;

  prep_nrm<<<4, 256, 0, stream>>>(normals, nrmp);

  // weights -> frag layout (c-MLPs are mlp 0..7, f-MLPs are 8..11)
  prep_w<29, 64, 32, 64><<<8, 256, 0, stream>>>(cW1, WLs, 0, 8, 0);
  prep_w<64, 64, 64, 64><<<16, 256, 0, stream>>>(cW2, WLs, 2048, 8, 0);
  prep_w<64, 64, 64, 64><<<16, 256, 0, stream>>>(cW3, WLs, 6144, 8, 0);
  prep_w<64, 24, 64, 32><<<8, 256, 0, stream>>>(cWo, WLs, 10240, 8, 0);
  prep_w<29, 64, 32, 64><<<4, 256, 0, stream>>>(fW1, WLs, 0, 4, 8);
  prep_w<64, 64, 64, 64><<<8, 256, 0, stream>>>(fW2, WLs, 2048, 4, 8);
  prep_w<64, 64, 64, 64><<<8, 256, 0, stream>>>(fW3, WLs, 6144, 4, 8);
  prep_w<64, 3, 64, 32><<<4, 256, 0, stream>>>(fWo, WLs, 10240, 4, 8);

  prep_b<<<2, 256, 0, stream>>>(cb1, BLs, 8, 64, 64, 0, 0);
  prep_b<<<2, 256, 0, stream>>>(cb2, BLs, 8, 64, 64, 64, 0);
  prep_b<<<2, 256, 0, stream>>>(cb3, BLs, 8, 64, 64, 128, 0);
  prep_b<<<1, 256, 0, stream>>>(cbo, BLs, 8, 24, 32, 192, 0);
  prep_b<<<1, 256, 0, stream>>>(fb1, BLs, 4, 64, 64, 0, 8);
  prep_b<<<1, 256, 0, stream>>>(fb2, BLs, 4, 64, 64, 64, 8);
  prep_b<<<1, 256, 0, stream>>>(fb3, BLs, 4, 64, 64, 128, 8);
  prep_b<<<1, 256, 0, stream>>>(fbo, BLs, 4, 3, 32, 192, 8);

  mlp_main<true, false><<<kNTGT, 512, 0, stream>>>(
      cent, cent, nrmp, areas, refl, WLs, BLs, 0, nullptr, nullptr, scalA,
      vecsA, nullptr, nullptr);
  mlp_main<false, false><<<kNTGT, 512, 0, stream>>>(
      cent, cent, nrmp, areas, refl, WLs, BLs, 4, scalA, vecsA, scalB, vecsB,
      nullptr, nullptr);
  mlp_main<false, true><<<kNPTS, 512, 0, stream>>>(
      pred, cent, nrmp, areas, refl, WLs, BLs, 8, scalB, vecsB, nullptr,
      nullptr, calib, outp);
}